// Round 8
// baseline (183.948 us; speedup 1.0000x reference)
//
#include <hip/hip_runtime.h>
#include <hip/hip_bf16.h>
#include <stdint.h>

// ---------------------------------------------------------------------------
// SelfAttn: B=4, W=H=64, C=256, C2=128, N=W*H=4096.
// pq = raw q buffer viewed [128,4096]  (Q_rows[n,c] = q_flat[c*4096+n])
// pv = raw v buffer viewed [256,4096]
// energy = Qrm @ Krm^T (K=128), softmax over keys (fixed ref m=0),
// O[n,c] = sum_m P[n,m] V[m,c];  final[b,c*4096+n] = gamma*O/l + x.
//
// R19 (resubmit; round-7 run was a container infra failure, kernel audited:
// uniform barriers, fixed trip counts, S-carry dataflow verified kt=0..31).
// R18 falsified chain-depth + swizzle theories (conflicts 3x'd; both
// reverted -> exact R10 attn body/layout). One remaining dependency theory:
// the 16 exp(S) consume S produced by MFMAs of the SAME barrier epoch ->
// wave drains its QK chain before softmax VALU starts; 2 waves/SIMD can't
// cover. Fix: S-carry pipeline. Iteration kt computes QK(kt+2) into Snew,
// exps S(kt+1) carried from LAST iteration (no MFMA dep this epoch), and
// PV(kt). All three phases mutually independent within an epoch. Values
// and accumulation order bit-identical; +~24 VGPR (Ssave/Snew).
// proj: Q-kind and K-kind blocks read the SAME x pixels -> merged into one
// block kind doing both 8-dt phases (grid 512->384, -16.7 MB x traffic).
// ---------------------------------------------------------------------------

typedef __attribute__((ext_vector_type(8)))  short short8;   // 8 x bf16
typedef __attribute__((ext_vector_type(4)))  float f32x4;
typedef __attribute__((ext_vector_type(16))) float f32x16;
typedef __attribute__((ext_vector_type(4)))  unsigned short u16x4;

#define MFMA16 __builtin_amdgcn_mfma_f32_16x16x32_bf16
#define MFMA32 __builtin_amdgcn_mfma_f32_32x32x16_bf16

__device__ __forceinline__ unsigned short f2bf(float f) {
    union { float f; uint32_t u; } v; v.f = f;
    return (unsigned short)((v.u + 0x8000u) >> 16);    // round-half-up
}
__device__ __forceinline__ float bf2f(unsigned short h) {
    union { uint32_t u; float f; } v; v.u = ((uint32_t)h) << 16;
    return v.f;
}
// packed f32x2 -> bf16x2 (v_cvt_pk_bf16_f32, RNE)
__device__ __forceinline__ uint32_t pkbf(float a, float b) {
    union { __hip_bfloat162 h; uint32_t u; } v;
    v.h = __float22bfloat162_rn(float2{a, b});
    return v.u;
}

// --- K1: Wt[512][256] bf16 (transposed, fused qkv) + bias[512] f32 ---------
__global__ void prep_w(const float* __restrict__ Wq, const float* __restrict__ bq,
                       const float* __restrict__ Wk, const float* __restrict__ bk,
                       const float* __restrict__ Wv, const float* __restrict__ bv,
                       unsigned short* __restrict__ Wt, float* __restrict__ bias) {
    int g = blockIdx.x * 256 + threadIdx.x;
    int c = g & 255, d = g >> 8;
    float val;
    if (d < 128)      val = Wq[c * 128 + d];
    else if (d < 256) val = Wk[c * 128 + (d - 128)];
    else              val = Wv[c * 256 + (d - 256)];
    Wt[d * 256 + c] = f2bf(val);
    if (g < 512) {
        float bb;
        if (g < 128)      bb = bq[g];
        else if (g < 256) bb = bk[g - 128];
        else              bb = bv[g - 256];
        bias[g] = bb;
    }
}

// --- K2: fused QKV projection. 384 blocks (R19):
//   [0,128)   QK-kind -> Q phase writes Qrm [n][128]; K phase writes Kp
//             (same x pixel-set loaded ONCE, both 8-dt phases)
//   [128,384) V-kind  -> Vp[m-chunk(256)][c(256)][k(16)] packed
__global__ __launch_bounds__(256) void proj(
        const float* __restrict__ x, const unsigned short* __restrict__ Wt,
        const float* __restrict__ bias,
        unsigned short* __restrict__ Qrm, unsigned short* __restrict__ Kp,
        unsigned short* __restrict__ Vp) {
    __shared__ unsigned short T[128 * 136];
    int bid = blockIdx.x;
    int tid = threadIdx.x;
    int wave = tid >> 6, lane = tid & 63;
    int l16 = lane & 15, quad = lane >> 4;

    int kind, b, a, vh = 0;
    if (bid < 128) { kind = 0; b = bid >> 5; a = bid & 31; }      // merged QK
    else           { kind = 2; int s = bid - 128; vh = s >> 7; b = (s >> 5) & 3; a = s & 31; }

    short8 af[2][8];
    #pragma unroll
    for (int g = 0; g < 2; ++g) {
        int p_local = wave * 32 + g * 16 + l16;
        int pix = (kind == 2) ? (b * 4096 + a * 128 + p_local)
                              : (b * 4096 + a + 32 * p_local);
        const float* xr = x + (size_t)pix * 256;
        #pragma unroll
        for (int kk = 0; kk < 8; ++kk) {
            f32x4 u0 = *(const f32x4*)(xr + kk * 32 + quad * 8);
            f32x4 u1 = *(const f32x4*)(xr + kk * 32 + quad * 8 + 4);
            union { short8 s; uint32_t u[4]; } h;
            h.u[0] = pkbf(u0[0], u0[1]); h.u[1] = pkbf(u0[2], u0[3]);
            h.u[2] = pkbf(u1[0], u1[1]); h.u[3] = pkbf(u1[2], u1[3]);
            af[g][kk] = h.s;
        }
    }

    if (kind == 0) {
        #pragma unroll 1
        for (int phase = 0; phase < 2; ++phase) {
            int dbase = phase * 128;
            #pragma unroll 1
            for (int dt = 0; dt < 8; ++dt) {
                int d = dbase + dt * 16 + l16;
                float bval = bias[d];
                f32x4 acc0 = {0.f,0.f,0.f,0.f}, acc1 = {0.f,0.f,0.f,0.f};
                #pragma unroll
                for (int kk = 0; kk < 8; ++kk) {
                    short8 wrow = *(const short8*)(Wt + d * 256 + kk * 32 + quad * 8);
                    acc0 = MFMA16(af[0][kk], wrow, acc0, 0, 0, 0);
                    acc1 = MFMA16(af[1][kk], wrow, acc1, 0, 0, 0);
                }
                #pragma unroll
                for (int g = 0; g < 2; ++g) {
                    f32x4 acc = g ? acc1 : acc0;
                    union { u16x4 v; uint32_t u[2]; } pk;
                    pk.u[0] = pkbf(acc[0] + bval, acc[1] + bval);
                    pk.u[1] = pkbf(acc[2] + bval, acc[3] + bval);
                    *(u16x4*)(T + (dt * 16 + l16) * 136 + wave * 32 + g * 16 + quad * 4) = pk.v;
                }
            }
            __syncthreads();
            if (phase == 0) {
                unsigned short* ob = Qrm + (b << 19) + a * 128 * 128;
                #pragma unroll
                for (int it = 0; it < 8; ++it) {
                    int ci = it * 256 + tid;
                    int row = ci >> 4, cj = ci & 15;
                    *(short8*)(ob + row * 128 + cj * 8) = *(const short8*)(T + row * 136 + cj * 8);
                }
                __syncthreads();                       // T reused by K phase
            } else {
                unsigned short* kb = Kp + (b << 19);
                #pragma unroll
                for (int it = 0; it < 8; ++it) {
                    int ci = it * 256 + tid;
                    int row = ci >> 4, cj = ci & 15;
                    *(short8*)(kb + (cj >> 1) * 65536 + (a * 128 + row) * 16 + (cj & 1) * 8)
                        = *(const short8*)(T + row * 136 + cj * 8);
                }
            }
        }
    } else {
        #pragma unroll 1
        for (int dt = 0; dt < 8; ++dt) {
            int d = 256 + vh * 128 + dt * 16 + l16;
            f32x4 acc0 = {0.f,0.f,0.f,0.f}, acc1 = {0.f,0.f,0.f,0.f};
            #pragma unroll
            for (int kk = 0; kk < 8; ++kk) {
                short8 wrow = *(const short8*)(Wt + d * 256 + kk * 32 + quad * 8);
                acc0 = MFMA16(wrow, af[0][kk], acc0, 0, 0, 0);   // A=W, B=x -> D^T
                acc1 = MFMA16(wrow, af[1][kk], acc1, 0, 0, 0);
            }
            int dvl = dt * 16 + quad * 4;
            f32x4 bv4 = *(const f32x4*)(bias + 256 + vh * 128 + dvl);
            #pragma unroll
            for (int g = 0; g < 2; ++g) {
                f32x4 acc = g ? acc1 : acc0;
                union { u16x4 v; uint32_t u[2]; } pk;
                pk.u[0] = pkbf(acc[0] + bv4[0], acc[1] + bv4[1]);
                pk.u[1] = pkbf(acc[2] + bv4[2], acc[3] + bv4[3]);
                int p_local = wave * 32 + g * 16 + l16;
                *(u16x4*)(T + p_local * 136 + dvl) = pk.v;
            }
        }
        __syncthreads();
        unsigned short* vb = Vp + (b << 20);
        #pragma unroll
        for (int it = 0; it < 8; ++it) {
            int cid = it * 256 + tid;
            int c_local = cid >> 8, w = cid & 255;
            int p_local = c_local * 16 + (w >> 4);
            int chunk = (w >> 4) * 16 + vh * 8 + ((w & 15) >> 1);
            *(short8*)(vb + chunk * 4096 + (a * 8 + c_local) * 16 + (w & 1) * 8)
                = *(const short8*)(T + p_local * 136 + (w & 15) * 8);
        }
    }
}

// --- K3: flash attention, R19 S-carry pipeline. ----------------------------
// grid 512 = 64 qtiles x (4 b x 2 ks); 64 q/block, 64-key tiles x 32,
// 32x32x16 MFMA, packed-coalesced K/V direct loads, Ps dbuf (R10 layout).
// Iteration kt: exp(S(kt+1)) [carried, no MFMA dep this epoch] +
// QK(kt+2)->Snew [consumed next epoch] + PV(kt). ONE __syncthreads.
__global__ __launch_bounds__(256, 2) void attn(
        const unsigned short* __restrict__ Qrm, const unsigned short* __restrict__ Kp,
        const unsigned short* __restrict__ Vp, unsigned short* __restrict__ Opart,
        float* __restrict__ Lpart) {
    __shared__ unsigned short Ps[2 * 64 * 72];         // P [q=64][m=64 +pad], x2

    int bid = blockIdx.x;
    int comb = bid & 7, qt = bid >> 3;                 // same (b,ks) -> same XCD
    int b = comb >> 1, ks = comb & 1;
    int tid = threadIdx.x, wave = tid >> 6, lane = tid & 63;
    int l32 = lane & 31, half = lane >> 5;
    int mt = wave & 1, nt = wave >> 1;

    const unsigned short* Qb = Qrm + (b << 19);
    const unsigned short* Kb = Kp + (b << 19);
    const unsigned short* Vb = Vp + (b << 20);

    int q0 = qt * 64;

    short8 qf[8];                                      // B=Q for wave's 32 queries
    {
        const unsigned short* qrow = Qb + (q0 + nt * 32 + l32) * 128 + half * 8;
        #pragma unroll
        for (int kk = 0; kk < 8; ++kk) qf[kk] = *(const short8*)(qrow + kk * 16);
    }

    f32x16 O[2][2];                                    // [qtile][ctile]
    #pragma unroll
    for (int i = 0; i < 2; ++i)
        #pragma unroll
        for (int j = 0; j < 2; ++j)
            #pragma unroll
            for (int r = 0; r < 16; ++r) O[i][j][r] = 0.f;
    float l_run = 0.f;                                 // own-half partial only

    const int m_base = ks * 2048;
    const int chunk_base = ks * 128;                   // m_base>>4
    const int kbase = (m_base + mt * 32 + l32) * 16 + half * 8;

    // ---- prologue: S(0)->Ps[0]; S(1)->Ssave; kf ends at K(2) --------------
    short8 kf[8];
    #pragma unroll
    for (int kk = 0; kk < 8; ++kk)
        kf[kk] = *(const short8*)(Kb + kk * 65536 + kbase);
    short8 vfrag[2][4];                                // V(0)
    #pragma unroll
    for (int c2 = 0; c2 < 2; ++c2)
        #pragma unroll
        for (int k2 = 0; k2 < 4; ++k2)
            vfrag[c2][k2] = *(const short8*)(Vb + (chunk_base + k2) * 4096
                              + ((wave * 2 + c2) * 32 + l32) * 16 + half * 8);
    {
        f32x16 S;
        #pragma unroll
        for (int r = 0; r < 16; ++r) S[r] = 0.f;
        #pragma unroll
        for (int kk = 0; kk < 8; ++kk) S = MFMA32(kf[kk], qf[kk], S, 0, 0, 0);
        #pragma unroll
        for (int g = 0; g < 4; ++g) {
            float p0 = __expf(S[g * 4 + 0]), p1 = __expf(S[g * 4 + 1]);
            float p2 = __expf(S[g * 4 + 2]), p3 = __expf(S[g * 4 + 3]);
            l_run += (p0 + p1) + (p2 + p3);
            union { u16x4 v; uint32_t u[2]; } pk;
            pk.u[0] = pkbf(p0, p1); pk.u[1] = pkbf(p2, p3);
            *(u16x4*)(Ps + (nt * 32 + l32) * 72 + mt * 32 + g * 8 + half * 4) = pk.v;
        }
    }
    f32x16 Ssave;                                      // S(1), carried
    {
        #pragma unroll
        for (int kk = 0; kk < 8; ++kk)                 // kf <- K(1)
            kf[kk] = *(const short8*)(Kb + kk * 65536 + 64 * 16 + kbase);
        #pragma unroll
        for (int r = 0; r < 16; ++r) Ssave[r] = 0.f;
        #pragma unroll
        for (int kk = 0; kk < 8; ++kk) Ssave = MFMA32(kf[kk], qf[kk], Ssave, 0, 0, 0);
        #pragma unroll
        for (int kk = 0; kk < 8; ++kk)                 // kf <- K(2)
            kf[kk] = *(const short8*)(Kb + kk * 65536 + 2 * 64 * 16 + kbase);
    }

    #pragma unroll 1
    for (int kt = 0; kt < 32; ++kt) {
        __syncthreads();   // Ps[kt&1] visible; PV(kt-1) done -> other buf free

        // (1) softmax of S(kt+1), carried from last epoch -- no MFMA dep.
        if (kt < 31) {
            unsigned short* Pn = Ps + ((kt + 1) & 1) * (64 * 72);
            #pragma unroll
            for (int g = 0; g < 4; ++g) {
                float p0 = __expf(Ssave[g * 4 + 0]), p1 = __expf(Ssave[g * 4 + 1]);
                float p2 = __expf(Ssave[g * 4 + 2]), p3 = __expf(Ssave[g * 4 + 3]);
                l_run += (p0 + p1) + (p2 + p3);
                union { u16x4 v; uint32_t u[2]; } pk;
                pk.u[0] = pkbf(p0, p1); pk.u[1] = pkbf(p2, p3);
                *(u16x4*)(Pn + (nt * 32 + l32) * 72 + mt * 32 + g * 8 + half * 4) = pk.v;
            }
        }

        // (2) QK(kt+2) -> Snew; consumed next epoch.
        f32x16 Snew;
        if (kt < 30) {
            #pragma unroll
            for (int r = 0; r < 16; ++r) Snew[r] = 0.f;
            #pragma unroll
            for (int kk = 0; kk < 8; ++kk) Snew = MFMA32(kf[kk], qf[kk], Snew, 0, 0, 0);
        }
        if (kt < 29) {                                 // kf <- K(kt+3)
            int kr = (kt + 3) * 64 * 16 + kbase;
            #pragma unroll
            for (int kk = 0; kk < 8; ++kk)
                kf[kk] = *(const short8*)(Kb + kk * 65536 + kr);
        }

        // (3) PV(kt): A = P rows (q) from Ps[kt&1], B = vfrag(kt)
        unsigned short* Pb = Ps + (kt & 1) * (64 * 72);
        #pragma unroll
        for (int k2 = 0; k2 < 4; ++k2) {
            short8 pa0 = *(const short8*)(Pb + (l32) * 72 + k2 * 16 + half * 8);
            short8 pa1 = *(const short8*)(Pb + (32 + l32) * 72 + k2 * 16 + half * 8);
            O[0][0] = MFMA32(pa0, vfrag[0][k2], O[0][0], 0, 0, 0);
            O[0][1] = MFMA32(pa0, vfrag[1][k2], O[0][1], 0, 0, 0);
            O[1][0] = MFMA32(pa1, vfrag[0][k2], O[1][0], 0, 0, 0);
            O[1][1] = MFMA32(pa1, vfrag[1][k2], O[1][1], 0, 0, 0);
        }

        if (kt < 31) {                                 // vfrag <- V(kt+1)
            int ch1 = chunk_base + (kt + 1) * 4;
            #pragma unroll
            for (int c2 = 0; c2 < 2; ++c2)
                #pragma unroll
                for (int k2 = 0; k2 < 4; ++k2)
                    vfrag[c2][k2] = *(const short8*)(Vb + (ch1 + k2) * 4096
                                      + ((wave * 2 + c2) * 32 + l32) * 16 + half * 8);
        }

        if (kt < 30) Ssave = Snew;                     // rotate carried S
    }

    // epilogue: unnormalized O + per-query l partials (cross-half sum here)
    l_run += __shfl_xor(l_run, 32);
    unsigned short* Op = Opart + ((size_t)(ks * 4 + b) << 20);
    #pragma unroll
    for (int q2 = 0; q2 < 2; ++q2)
        #pragma unroll
        for (int c2 = 0; c2 < 2; ++c2) {
            int c = (wave * 2 + c2) * 32 + l32;
            #pragma unroll
            for (int r = 0; r < 16; ++r) {
                int n = q0 + q2 * 32 + (r & 3) + 8 * (r >> 2) + 4 * half;
                Op[(size_t)n * 256 + c] = f2bf(O[q2][c2][r]);
            }
        }
    if (half == 0) {
        int n = q0 + nt * 32 + l32;
        Lpart[((ks * 2 + mt) * 4 + b) * 4096 + n] = l_run;
    }
}

// --- K4: merge 2 key-splits, gamma*O/l + x, transpose [n,c]->[c,n] ---------
__global__ __launch_bounds__(256) void merge_out(
        const unsigned short* __restrict__ Opart, const float* __restrict__ Lpart,
        const float* __restrict__ x, const float* __restrict__ gamma,
        float* __restrict__ out) {
    __shared__ float tile[64 * 257];                   // [n=64][c=256 +pad]
    __shared__ float wsm[64];
    int b  = blockIdx.x >> 6;
    int n0 = (blockIdx.x & 63) << 6;
    int tid = threadIdx.x;
    float g = gamma[0];
    if (tid < 64) {
        int n = n0 + tid;
        float L = 0.f;
        #pragma unroll
        for (int s = 0; s < 4; ++s) L += Lpart[(s * 4 + b) * 4096 + n];
        wsm[tid] = g / L;
    }
    __syncthreads();
    int nl1 = tid >> 5, cb1 = (tid & 31) * 8;
    const unsigned short* Op0 = Opart + ((size_t)b << 20);
    const unsigned short* Op1 = Opart + ((size_t)(4 + b) << 20);
    #pragma unroll
    for (int i = 0; i < 8; ++i) {
        int nl = i * 8 + nl1;
        size_t off = (size_t)(n0 + nl) * 256 + cb1;
        short8 o0 = *(const short8*)(Op0 + off);
        short8 o1 = *(const short8*)(Op1 + off);
        float w = wsm[nl];
        float* tr = tile + nl * 257 + cb1;
        #pragma unroll
        for (int e = 0; e < 8; ++e)
            tr[e] = (bf2f((unsigned short)o0[e]) + bf2f((unsigned short)o1[e])) * w;
    }
    __syncthreads();
    int cg = tid >> 4, nq = (tid & 15) * 4;
    #pragma unroll
    for (int it = 0; it < 16; ++it) {
        int c = it * 16 + cg;
        size_t idx = ((size_t)b << 20) + (size_t)c * 4096 + n0 + nq;
        f32x4 xv = *(const f32x4*)(x + idx);
        f32x4 ov;
        #pragma unroll
        for (int e = 0; e < 4; ++e) ov[e] = tile[(nq + e) * 257 + c] + xv[e];
        *(f32x4*)(out + idx) = ov;
    }
}

// ---------------------------------------------------------------------------
extern "C" void kernel_launch(void* const* d_in, const int* in_sizes, int n_in,
                              void* d_out, int out_size, void* d_ws, size_t ws_size,
                              hipStream_t stream) {
    const float* x     = (const float*)d_in[0];
    const float* Wq    = (const float*)d_in[1];
    const float* bq    = (const float*)d_in[2];
    const float* Wk    = (const float*)d_in[3];
    const float* bk    = (const float*)d_in[4];
    const float* Wv    = (const float*)d_in[5];
    const float* bv    = (const float*)d_in[6];
    const float* gamma = (const float*)d_in[7];
    float* out = (float*)d_out;

    if (ws_size < 34080768u) return;   // need ~33 MB scratch

    char* ws = (char*)d_ws;
    unsigned short* Wt    = (unsigned short*)(ws);             //    262,144 B
    float*          bias  = (float*)        (ws +   262144);   //      2,048 B
    unsigned short* Qrm   = (unsigned short*)(ws +   264192);  //  4,194,304 B
    unsigned short* Kp    = (unsigned short*)(ws +  4458496);  //  4,194,304 B
    unsigned short* Vp    = (unsigned short*)(ws +  8652800);  //  8,388,608 B
    unsigned short* Opart = (unsigned short*)(ws + 17041408);  // 16,777,216 B
    float*          Lpart = (float*)        (ws + 33818624);   //    262,144 B

    prep_w   <<<512, 256, 0, stream>>>(Wq, bq, Wk, bk, Wv, bv, Wt, bias);
    proj     <<<384, 256, 0, stream>>>(x, Wt, bias, Qrm, Kp, Vp);
    attn     <<<512, 256, 0, stream>>>(Qrm, Kp, Vp, Opart, Lpart);
    merge_out<<<256, 256, 0, stream>>>(Opart, Lpart, x, gamma, out);
}

// Round 9
// 172.181 us; speedup vs baseline: 1.0683x; 1.0683x over previous
//
#include <hip/hip_runtime.h>
#include <hip/hip_bf16.h>
#include <stdint.h>

// ---------------------------------------------------------------------------
// SelfAttn: B=4, W=H=64, C=256, C2=128, N=W*H=4096.
// pq = raw q buffer viewed [128,4096]  (Q_rows[n,c] = q_flat[c*4096+n])
// pv = raw v buffer viewed [256,4096]
// energy = Qrm @ Krm^T (K=128), softmax over keys (fixed ref m=0),
// O[n,c] = sum_m P[n,m] V[m,c];  final[b,c*4096+n] = gamma*O/l + x.
//
// R20: six single-variable theories falsified (R14-R19); every addition to
// the R10 body lost. The one clean dose-response point: R15 HALVED the
// MFMA-per-barrier-epoch (24->12) and attn went 69->89us -> per-epoch
// overhead is ~fixed per epoch. Test the other direction: DOUBLE the epoch
// (48 MFMA/wave, 16 barriers instead of 32) via 2x tile unroll + 4-slot Ps
// ring. Same instruction mix as R10 (same loads/MFMA/exp counts), S_A dies
// before S_B so register pressure ~R10. proj reverted to R10 512-block form
// (R19 merge caused imbalance).
// ---------------------------------------------------------------------------

typedef __attribute__((ext_vector_type(8)))  short short8;   // 8 x bf16
typedef __attribute__((ext_vector_type(4)))  float f32x4;
typedef __attribute__((ext_vector_type(16))) float f32x16;
typedef __attribute__((ext_vector_type(4)))  unsigned short u16x4;

#define MFMA16 __builtin_amdgcn_mfma_f32_16x16x32_bf16
#define MFMA32 __builtin_amdgcn_mfma_f32_32x32x16_bf16

__device__ __forceinline__ unsigned short f2bf(float f) {
    union { float f; uint32_t u; } v; v.f = f;
    return (unsigned short)((v.u + 0x8000u) >> 16);    // round-half-up
}
__device__ __forceinline__ float bf2f(unsigned short h) {
    union { uint32_t u; float f; } v; v.u = ((uint32_t)h) << 16;
    return v.f;
}
// packed f32x2 -> bf16x2 (v_cvt_pk_bf16_f32, RNE)
__device__ __forceinline__ uint32_t pkbf(float a, float b) {
    union { __hip_bfloat162 h; uint32_t u; } v;
    v.h = __float22bfloat162_rn(float2{a, b});
    return v.u;
}

// --- K1: Wt[512][256] bf16 (transposed, fused qkv) + bias[512] f32 ---------
__global__ void prep_w(const float* __restrict__ Wq, const float* __restrict__ bq,
                       const float* __restrict__ Wk, const float* __restrict__ bk,
                       const float* __restrict__ Wv, const float* __restrict__ bv,
                       unsigned short* __restrict__ Wt, float* __restrict__ bias) {
    int g = blockIdx.x * 256 + threadIdx.x;
    int c = g & 255, d = g >> 8;
    float val;
    if (d < 128)      val = Wq[c * 128 + d];
    else if (d < 256) val = Wk[c * 128 + (d - 128)];
    else              val = Wv[c * 256 + (d - 256)];
    Wt[d * 256 + c] = f2bf(val);
    if (g < 512) {
        float bb;
        if (g < 128)      bb = bq[g];
        else if (g < 256) bb = bk[g - 128];
        else              bb = bv[g - 256];
        bias[g] = bb;
    }
}

// --- K2: fused QKV projection. 512 uniform blocks (R10):
//   [0,128)   Q-kind -> Qrm [n][128] tiles
//   [128,256) K-kind -> Kp[c-chunk(8)][m(4096)][k(16)] packed
//   [256,512) V-kind -> Vp[m-chunk(256)][c(256)][k(16)] packed
__global__ __launch_bounds__(256) void proj(
        const float* __restrict__ x, const unsigned short* __restrict__ Wt,
        const float* __restrict__ bias,
        unsigned short* __restrict__ Qrm, unsigned short* __restrict__ Kp,
        unsigned short* __restrict__ Vp) {
    __shared__ unsigned short T[128 * 136];
    int bid = blockIdx.x;
    int tid = threadIdx.x;
    int wave = tid >> 6, lane = tid & 63;
    int l16 = lane & 15, quad = lane >> 4;

    int kind, b, a, vh = 0;
    if (bid < 256) { kind = bid >> 7; int s = bid & 127; b = s >> 5; a = s & 31; }
    else           { kind = 2; int s = bid - 256; vh = s >> 7; b = (s >> 5) & 3; a = s & 31; }

    short8 af[2][8];
    #pragma unroll
    for (int g = 0; g < 2; ++g) {
        int p_local = wave * 32 + g * 16 + l16;
        int pix = (kind == 2) ? (b * 4096 + a * 128 + p_local)
                              : (b * 4096 + a + 32 * p_local);
        const float* xr = x + (size_t)pix * 256;
        #pragma unroll
        for (int kk = 0; kk < 8; ++kk) {
            f32x4 u0 = *(const f32x4*)(xr + kk * 32 + quad * 8);
            f32x4 u1 = *(const f32x4*)(xr + kk * 32 + quad * 8 + 4);
            union { short8 s; uint32_t u[4]; } h;
            h.u[0] = pkbf(u0[0], u0[1]); h.u[1] = pkbf(u0[2], u0[3]);
            h.u[2] = pkbf(u1[0], u1[1]); h.u[3] = pkbf(u1[2], u1[3]);
            af[g][kk] = h.s;
        }
    }

    if (kind < 2) {
        int dbase = kind * 128;
        #pragma unroll 1
        for (int dt = 0; dt < 8; ++dt) {
            int d = dbase + dt * 16 + l16;
            float bval = bias[d];
            f32x4 acc0 = {0.f,0.f,0.f,0.f}, acc1 = {0.f,0.f,0.f,0.f};
            #pragma unroll
            for (int kk = 0; kk < 8; ++kk) {
                short8 wrow = *(const short8*)(Wt + d * 256 + kk * 32 + quad * 8);
                acc0 = MFMA16(af[0][kk], wrow, acc0, 0, 0, 0);
                acc1 = MFMA16(af[1][kk], wrow, acc1, 0, 0, 0);
            }
            #pragma unroll
            for (int g = 0; g < 2; ++g) {
                f32x4 acc = g ? acc1 : acc0;
                union { u16x4 v; uint32_t u[2]; } pk;
                pk.u[0] = pkbf(acc[0] + bval, acc[1] + bval);
                pk.u[1] = pkbf(acc[2] + bval, acc[3] + bval);
                *(u16x4*)(T + (dt * 16 + l16) * 136 + wave * 32 + g * 16 + quad * 4) = pk.v;
            }
        }
        __syncthreads();
        if (kind == 0) {
            unsigned short* ob = Qrm + (b << 19) + a * 128 * 128;
            #pragma unroll
            for (int it = 0; it < 8; ++it) {
                int ci = it * 256 + tid;
                int row = ci >> 4, cj = ci & 15;
                *(short8*)(ob + row * 128 + cj * 8) = *(const short8*)(T + row * 136 + cj * 8);
            }
        } else {
            unsigned short* kb = Kp + (b << 19);
            #pragma unroll
            for (int it = 0; it < 8; ++it) {
                int ci = it * 256 + tid;
                int row = ci >> 4, cj = ci & 15;
                *(short8*)(kb + (cj >> 1) * 65536 + (a * 128 + row) * 16 + (cj & 1) * 8)
                    = *(const short8*)(T + row * 136 + cj * 8);
            }
        }
    } else {
        #pragma unroll 1
        for (int dt = 0; dt < 8; ++dt) {
            int d = 256 + vh * 128 + dt * 16 + l16;
            f32x4 acc0 = {0.f,0.f,0.f,0.f}, acc1 = {0.f,0.f,0.f,0.f};
            #pragma unroll
            for (int kk = 0; kk < 8; ++kk) {
                short8 wrow = *(const short8*)(Wt + d * 256 + kk * 32 + quad * 8);
                acc0 = MFMA16(wrow, af[0][kk], acc0, 0, 0, 0);   // A=W, B=x -> D^T
                acc1 = MFMA16(wrow, af[1][kk], acc1, 0, 0, 0);
            }
            int dvl = dt * 16 + quad * 4;
            f32x4 bv4 = *(const f32x4*)(bias + 256 + vh * 128 + dvl);
            #pragma unroll
            for (int g = 0; g < 2; ++g) {
                f32x4 acc = g ? acc1 : acc0;
                union { u16x4 v; uint32_t u[2]; } pk;
                pk.u[0] = pkbf(acc[0] + bv4[0], acc[1] + bv4[1]);
                pk.u[1] = pkbf(acc[2] + bv4[2], acc[3] + bv4[3]);
                int p_local = wave * 32 + g * 16 + l16;
                *(u16x4*)(T + p_local * 136 + dvl) = pk.v;
            }
        }
        __syncthreads();
        unsigned short* vb = Vp + (b << 20);
        #pragma unroll
        for (int it = 0; it < 8; ++it) {
            int cid = it * 256 + tid;
            int c_local = cid >> 8, w = cid & 255;
            int p_local = c_local * 16 + (w >> 4);
            int chunk = (w >> 4) * 16 + vh * 8 + ((w & 15) >> 1);
            *(short8*)(vb + chunk * 4096 + (a * 8 + c_local) * 16 + (w & 1) * 8)
                = *(const short8*)(T + p_local * 136 + (w & 15) * 8);
        }
    }
}

// --- K3: flash attention, R20 double-epoch (2 tiles per barrier). ----------
// grid 512 = 64 qtiles x (4 b x 2 ks); 64 q/block, 64-key tiles, 16 epochs
// x 2 tiles, 32x32x16 MFMA, packed-coalesced K/V direct loads, Ps 4-ring.
// Epoch e: QK(2e+2) -> PV(2e) -> softmaxA -> QK(2e+3) -> PV(2e+1) ->
// softmaxB, ONE __syncthreads. 48 MFMA/wave/epoch vs R10's 24.
__global__ __launch_bounds__(256, 2) void attn(
        const unsigned short* __restrict__ Qrm, const unsigned short* __restrict__ Kp,
        const unsigned short* __restrict__ Vp, unsigned short* __restrict__ Opart,
        float* __restrict__ Lpart) {
    __shared__ unsigned short Ps[4 * 64 * 72];         // P [q=64][m=64 +pad], x4 ring

    int bid = blockIdx.x;
    int comb = bid & 7, qt = bid >> 3;                 // same (b,ks) -> same XCD
    int b = comb >> 1, ks = comb & 1;
    int tid = threadIdx.x, wave = tid >> 6, lane = tid & 63;
    int l32 = lane & 31, half = lane >> 5;
    int mt = wave & 1, nt = wave >> 1;

    const unsigned short* Qb = Qrm + (b << 19);
    const unsigned short* Kb = Kp + (b << 19);
    const unsigned short* Vb = Vp + (b << 20);

    int q0 = qt * 64;

    short8 qf[8];                                      // B=Q for wave's 32 queries
    {
        const unsigned short* qrow = Qb + (q0 + nt * 32 + l32) * 128 + half * 8;
        #pragma unroll
        for (int kk = 0; kk < 8; ++kk) qf[kk] = *(const short8*)(qrow + kk * 16);
    }

    f32x16 O[2][2];                                    // [qtile][ctile]
    #pragma unroll
    for (int i = 0; i < 2; ++i)
        #pragma unroll
        for (int j = 0; j < 2; ++j)
            #pragma unroll
            for (int r = 0; r < 16; ++r) O[i][j][r] = 0.f;
    float l_run = 0.f;                                 // own-half partial only

    const int m_base = ks * 2048;
    const int chunk_base = ks * 128;                   // m_base>>4
    const int kbase = (m_base + mt * 32 + l32) * 16 + half * 8;

    // ---- prologue: softmax(0)->Ps[0], softmax(1)->Ps[1]; kf ends at K(2) --
    short8 kf[8];
    #pragma unroll
    for (int kk = 0; kk < 8; ++kk)
        kf[kk] = *(const short8*)(Kb + kk * 65536 + kbase);
    short8 vfrag[2][4];                                // V(0)
    #pragma unroll
    for (int c2 = 0; c2 < 2; ++c2)
        #pragma unroll
        for (int k2 = 0; k2 < 4; ++k2)
            vfrag[c2][k2] = *(const short8*)(Vb + (chunk_base + k2) * 4096
                              + ((wave * 2 + c2) * 32 + l32) * 16 + half * 8);
    #pragma unroll 1
    for (int pt = 0; pt < 2; ++pt) {
        f32x16 S;
        #pragma unroll
        for (int r = 0; r < 16; ++r) S[r] = 0.f;
        #pragma unroll
        for (int kk = 0; kk < 8; ++kk) S = MFMA32(kf[kk], qf[kk], S, 0, 0, 0);
        unsigned short* Pn = Ps + pt * (64 * 72);
        #pragma unroll
        for (int g = 0; g < 4; ++g) {
            float p0 = __expf(S[g * 4 + 0]), p1 = __expf(S[g * 4 + 1]);
            float p2 = __expf(S[g * 4 + 2]), p3 = __expf(S[g * 4 + 3]);
            l_run += (p0 + p1) + (p2 + p3);
            union { u16x4 v; uint32_t u[2]; } pk;
            pk.u[0] = pkbf(p0, p1); pk.u[1] = pkbf(p2, p3);
            *(u16x4*)(Pn + (nt * 32 + l32) * 72 + mt * 32 + g * 8 + half * 4) = pk.v;
        }
        #pragma unroll
        for (int kk = 0; kk < 8; ++kk)                 // kf <- K(pt+1)
            kf[kk] = *(const short8*)(Kb + kk * 65536 + (pt + 1) * 64 * 16 + kbase);
    }

    #pragma unroll 1
    for (int e = 0; e < 16; ++e) {
        __syncthreads();   // epoch e-1 Ps writes visible; its reads complete
        const int t0 = 2 * e;

        // (1) QK(t0+2) -> SA; (2) kf <- K(t0+3) (used at step 6)
        f32x16 SA;
        if (e < 15) {
            #pragma unroll
            for (int r = 0; r < 16; ++r) SA[r] = 0.f;
            #pragma unroll
            for (int kk = 0; kk < 8; ++kk) SA = MFMA32(kf[kk], qf[kk], SA, 0, 0, 0);
            int kr = (t0 + 3) * 64 * 16 + kbase;
            #pragma unroll
            for (int kk = 0; kk < 8; ++kk)
                kf[kk] = *(const short8*)(Kb + kk * 65536 + kr);
        }

        // (3) PV(t0): Ps slot t0&3 (written epoch e-1), vfrag = V(t0)
        {
            unsigned short* Pb = Ps + (t0 & 3) * (64 * 72);
            #pragma unroll
            for (int k2 = 0; k2 < 4; ++k2) {
                short8 pa0 = *(const short8*)(Pb + (l32) * 72 + k2 * 16 + half * 8);
                short8 pa1 = *(const short8*)(Pb + (32 + l32) * 72 + k2 * 16 + half * 8);
                O[0][0] = MFMA32(pa0, vfrag[0][k2], O[0][0], 0, 0, 0);
                O[0][1] = MFMA32(pa0, vfrag[1][k2], O[0][1], 0, 0, 0);
                O[1][0] = MFMA32(pa1, vfrag[0][k2], O[1][0], 0, 0, 0);
                O[1][1] = MFMA32(pa1, vfrag[1][k2], O[1][1], 0, 0, 0);
            }
        }

        // (4) vfrag <- V(t0+1) (used at step 7 this epoch)
        {
            int ch1 = chunk_base + (t0 + 1) * 4;
            #pragma unroll
            for (int c2 = 0; c2 < 2; ++c2)
                #pragma unroll
                for (int k2 = 0; k2 < 4; ++k2)
                    vfrag[c2][k2] = *(const short8*)(Vb + (ch1 + k2) * 4096
                                      + ((wave * 2 + c2) * 32 + l32) * 16 + half * 8);
        }

        // (5) softmax SA -> Ps slot (t0+2)&3 (slot's readers ran epoch e-1)
        if (e < 15) {
            unsigned short* Pn = Ps + ((t0 + 2) & 3) * (64 * 72);
            #pragma unroll
            for (int g = 0; g < 4; ++g) {
                float p0 = __expf(SA[g * 4 + 0]), p1 = __expf(SA[g * 4 + 1]);
                float p2 = __expf(SA[g * 4 + 2]), p3 = __expf(SA[g * 4 + 3]);
                l_run += (p0 + p1) + (p2 + p3);
                union { u16x4 v; uint32_t u[2]; } pk;
                pk.u[0] = pkbf(p0, p1); pk.u[1] = pkbf(p2, p3);
                *(u16x4*)(Pn + (nt * 32 + l32) * 72 + mt * 32 + g * 8 + half * 4) = pk.v;
            }
        }

        // (6) QK(t0+3) -> SB (kf from step 2, >=1 PV-block distance)
        f32x16 SB;
        if (e < 15) {
            #pragma unroll
            for (int r = 0; r < 16; ++r) SB[r] = 0.f;
            #pragma unroll
            for (int kk = 0; kk < 8; ++kk) SB = MFMA32(kf[kk], qf[kk], SB, 0, 0, 0);
        }

        // (7) PV(t0+1): Ps slot (t0+1)&3, vfrag = V(t0+1)
        {
            unsigned short* Pb = Ps + ((t0 + 1) & 3) * (64 * 72);
            #pragma unroll
            for (int k2 = 0; k2 < 4; ++k2) {
                short8 pa0 = *(const short8*)(Pb + (l32) * 72 + k2 * 16 + half * 8);
                short8 pa1 = *(const short8*)(Pb + (32 + l32) * 72 + k2 * 16 + half * 8);
                O[0][0] = MFMA32(pa0, vfrag[0][k2], O[0][0], 0, 0, 0);
                O[0][1] = MFMA32(pa0, vfrag[1][k2], O[0][1], 0, 0, 0);
                O[1][0] = MFMA32(pa1, vfrag[0][k2], O[1][0], 0, 0, 0);
                O[1][1] = MFMA32(pa1, vfrag[1][k2], O[1][1], 0, 0, 0);
            }
        }

        // (8) vfrag <- V(t0+2) (for next epoch step 3)
        if (e < 15) {
            int ch1 = chunk_base + (t0 + 2) * 4;
            #pragma unroll
            for (int c2 = 0; c2 < 2; ++c2)
                #pragma unroll
                for (int k2 = 0; k2 < 4; ++k2)
                    vfrag[c2][k2] = *(const short8*)(Vb + (ch1 + k2) * 4096
                                      + ((wave * 2 + c2) * 32 + l32) * 16 + half * 8);
        }

        // (9) softmax SB -> Ps slot (t0+3)&3
        if (e < 15) {
            unsigned short* Pn = Ps + ((t0 + 3) & 3) * (64 * 72);
            #pragma unroll
            for (int g = 0; g < 4; ++g) {
                float p0 = __expf(SB[g * 4 + 0]), p1 = __expf(SB[g * 4 + 1]);
                float p2 = __expf(SB[g * 4 + 2]), p3 = __expf(SB[g * 4 + 3]);
                l_run += (p0 + p1) + (p2 + p3);
                union { u16x4 v; uint32_t u[2]; } pk;
                pk.u[0] = pkbf(p0, p1); pk.u[1] = pkbf(p2, p3);
                *(u16x4*)(Pn + (nt * 32 + l32) * 72 + mt * 32 + g * 8 + half * 4) = pk.v;
            }
        }

        // (10) kf <- K(t0+4) (for next epoch step 1)
        if (e < 14) {
            int kr = (t0 + 4) * 64 * 16 + kbase;
            #pragma unroll
            for (int kk = 0; kk < 8; ++kk)
                kf[kk] = *(const short8*)(Kb + kk * 65536 + kr);
        }
    }

    // epilogue: unnormalized O + per-query l partials (cross-half sum here)
    l_run += __shfl_xor(l_run, 32);
    unsigned short* Op = Opart + ((size_t)(ks * 4 + b) << 20);
    #pragma unroll
    for (int q2 = 0; q2 < 2; ++q2)
        #pragma unroll
        for (int c2 = 0; c2 < 2; ++c2) {
            int c = (wave * 2 + c2) * 32 + l32;
            #pragma unroll
            for (int r = 0; r < 16; ++r) {
                int n = q0 + q2 * 32 + (r & 3) + 8 * (r >> 2) + 4 * half;
                Op[(size_t)n * 256 + c] = f2bf(O[q2][c2][r]);
            }
        }
    if (half == 0) {
        int n = q0 + nt * 32 + l32;
        Lpart[((ks * 2 + mt) * 4 + b) * 4096 + n] = l_run;
    }
}

// --- K4: merge 2 key-splits, gamma*O/l + x, transpose [n,c]->[c,n] ---------
__global__ __launch_bounds__(256) void merge_out(
        const unsigned short* __restrict__ Opart, const float* __restrict__ Lpart,
        const float* __restrict__ x, const float* __restrict__ gamma,
        float* __restrict__ out) {
    __shared__ float tile[64 * 257];                   // [n=64][c=256 +pad]
    __shared__ float wsm[64];
    int b  = blockIdx.x >> 6;
    int n0 = (blockIdx.x & 63) << 6;
    int tid = threadIdx.x;
    float g = gamma[0];
    if (tid < 64) {
        int n = n0 + tid;
        float L = 0.f;
        #pragma unroll
        for (int s = 0; s < 4; ++s) L += Lpart[(s * 4 + b) * 4096 + n];
        wsm[tid] = g / L;
    }
    __syncthreads();
    int nl1 = tid >> 5, cb1 = (tid & 31) * 8;
    const unsigned short* Op0 = Opart + ((size_t)b << 20);
    const unsigned short* Op1 = Opart + ((size_t)(4 + b) << 20);
    #pragma unroll
    for (int i = 0; i < 8; ++i) {
        int nl = i * 8 + nl1;
        size_t off = (size_t)(n0 + nl) * 256 + cb1;
        short8 o0 = *(const short8*)(Op0 + off);
        short8 o1 = *(const short8*)(Op1 + off);
        float w = wsm[nl];
        float* tr = tile + nl * 257 + cb1;
        #pragma unroll
        for (int e = 0; e < 8; ++e)
            tr[e] = (bf2f((unsigned short)o0[e]) + bf2f((unsigned short)o1[e])) * w;
    }
    __syncthreads();
    int cg = tid >> 4, nq = (tid & 15) * 4;
    #pragma unroll
    for (int it = 0; it < 16; ++it) {
        int c = it * 16 + cg;
        size_t idx = ((size_t)b << 20) + (size_t)c * 4096 + n0 + nq;
        f32x4 xv = *(const f32x4*)(x + idx);
        f32x4 ov;
        #pragma unroll
        for (int e = 0; e < 4; ++e) ov[e] = tile[(nq + e) * 257 + c] + xv[e];
        *(f32x4*)(out + idx) = ov;
    }
}

// ---------------------------------------------------------------------------
extern "C" void kernel_launch(void* const* d_in, const int* in_sizes, int n_in,
                              void* d_out, int out_size, void* d_ws, size_t ws_size,
                              hipStream_t stream) {
    const float* x     = (const float*)d_in[0];
    const float* Wq    = (const float*)d_in[1];
    const float* bq    = (const float*)d_in[2];
    const float* Wk    = (const float*)d_in[3];
    const float* bk    = (const float*)d_in[4];
    const float* Wv    = (const float*)d_in[5];
    const float* bv    = (const float*)d_in[6];
    const float* gamma = (const float*)d_in[7];
    float* out = (float*)d_out;

    if (ws_size < 34080768u) return;   // need ~33 MB scratch

    char* ws = (char*)d_ws;
    unsigned short* Wt    = (unsigned short*)(ws);             //    262,144 B
    float*          bias  = (float*)        (ws +   262144);   //      2,048 B
    unsigned short* Qrm   = (unsigned short*)(ws +   264192);  //  4,194,304 B
    unsigned short* Kp    = (unsigned short*)(ws +  4458496);  //  4,194,304 B
    unsigned short* Vp    = (unsigned short*)(ws +  8652800);  //  8,388,608 B
    unsigned short* Opart = (unsigned short*)(ws + 17041408);  // 16,777,216 B
    float*          Lpart = (float*)        (ws + 33818624);   //    262,144 B

    prep_w   <<<512, 256, 0, stream>>>(Wq, bq, Wk, bk, Wv, bv, Wt, bias);
    proj     <<<512, 256, 0, stream>>>(x, Wt, bias, Qrm, Kp, Vp);
    attn     <<<512, 256, 0, stream>>>(Qrm, Kp, Vp, Opart, Lpart);
    merge_out<<<256, 256, 0, stream>>>(Opart, Lpart, x, gamma, out);
}